// Round 1
// baseline (1854.543 us; speedup 1.0000x reference)
//
#include <hip/hip_runtime.h>

// TreecrfLossSRL: inside algorithm (logsumexp semiring) for span tree-CRF.
// B=64, N=256. Two CYK passes (ob / allv) -> scalar (logz - marg).sum()/denom.
//
// Layout: one block per (batch, score-type) chart; chart lives in global ws,
// triangular-packed by width-layer: layer w (1..N) has N-w+1 entries,
// entry (i,w) at layer_start(w)+i.

#define NN 256
#define BATCH 64
#define NEGV -1000000000.0f
#define TRI (NN * (NN + 1) / 2)     /* 32896 floats per chart */
#define NCHART (2 * BATCH)          /* 128 charts */
#define RES_OFF ((size_t)NCHART * TRI)
#define LEN_OFF (RES_OFF + NCHART)

__device__ __forceinline__ int layer_start(int w) {
    // (w-1)*N - (w-1)(w-2)/2
    return ((w - 1) << 8) - (((w - 1) * (w - 2)) >> 1);
}

// score at span [i, j] for type t (0 = ob/constrained, 1 = allv)
__device__ __forceinline__ float score_at(const float* __restrict__ logits,
                                          const int* __restrict__ spans_ind,
                                          const void* __restrict__ span_mask,
                                          int isb, int t, int b, int i, int j) {
    size_t sidx = ((size_t)b * NN + i) * NN + j;
    float l0 = logits[2 * sidx];
    float l1 = logits[2 * sidx + 1];
    if (t) {
        float mx = fmaxf(l0, l1), mn = fminf(l0, l1);
        return mx + log1pf(__expf(mn - mx));
    } else {
        bool sind = (spans_ind[sidx] == 2);
        bool sm = isb ? (((const unsigned char*)span_mask)[sidx] != 0)
                      : (((const int*)span_mask)[sidx] != 0);
        float s0 = (sm || sind)  ? NEGV : l0;
        float s1 = (sm || !sind) ? NEGV : l1;
        float mx = fmaxf(s0, s1), mn = fminf(s0, s1);
        return mx + log1pf(__expf(mn - mx));
    }
}

__global__ __launch_bounds__(1024) void cyk_kernel(
    const float* __restrict__ logits,     // [B,N,N,2] f32
    const int* __restrict__ spans_ind,    // [B,N,N] i32
    const void* __restrict__ maskspan,    // [B,N,N] bool (byte or i32)
    const void* __restrict__ span_mask,   // [B,N,N] bool
    float* __restrict__ ws) {
    const int c = blockIdx.x;
    const int b = c >> 1;
    const int t = c & 1;
    float* chart = ws + (size_t)c * TRI;

    __shared__ int s_len;
    __shared__ int s_isb;
    if (threadIdx.x == 0) {
        s_len = 0;
        unsigned probe = *(const unsigned*)maskspan;
        s_isb = (probe > 1u) ? 1 : 0;  // byte-packed bools -> 0x01010101
    }
    __syncthreads();
    const int isb = s_isb;

    // lens[b] = sum_j maskspan[b,0,j]
    if (threadIdx.x < NN) {
        size_t off = (size_t)b * NN * NN + threadIdx.x;
        int v = isb ? (((const unsigned char*)maskspan)[off] ? 1 : 0)
                    : (((const int*)maskspan)[off] ? 1 : 0);
        atomicAdd(&s_len, v);
    }

    // level 1 init: A(i,1) = D(i,1) = score[i,i]
    if (threadIdx.x < NN) {
        int i = threadIdx.x;
        chart[i] = score_at(logits, spans_ind, span_mask, isb, t, b, i, i);
    }
    __syncthreads();

    for (int w = 2; w <= NN; ++w) {
        const int E = NN - w + 1;   // valid entries at this width
        const int T = w - 1;        // split points per entry
        int P = 1;                  // sub-lanes per entry (pow2, <=64, wave-local)
        while (P < 64 && ((P << 1) * E) <= 1024) P <<= 1;
        int shift = 31 - __clz(P);
        const int g = (int)threadIdx.x >> shift;  // entry index
        const int s = (int)threadIdx.x & (P - 1); // sub-lane

        if (g < E) {
            float m = -1e30f, sum = 0.0f;
            for (int u = 1 + s; u <= T; u += P) {
                float left  = chart[layer_start(u) + g];
                float right = chart[layer_start(w - u) + g + u];
                float tv = left + right;
                if (tv > m) { sum = sum * __expf(m - tv) + 1.0f; m = tv; }
                else        { sum += __expf(tv - m); }
            }
            // wave-local (m,s) tree combine across P sub-lanes
            for (int d = P >> 1; d > 0; d >>= 1) {
                float m2 = __shfl_xor(m, d);
                float s2 = __shfl_xor(sum, d);
                float mn = fmaxf(m, m2);
                sum = sum * __expf(m - mn) + s2 * __expf(m2 - mn);
                m = mn;
            }
            if (s == 0) {
                float dsc = score_at(logits, spans_ind, span_mask, isb, t, b,
                                     g, g + w - 1);
                chart[layer_start(w) + g] = dsc + m + __logf(sum);
            }
        }
        __syncthreads();
    }

    if (threadIdx.x == 0) {
        int len = s_len;
        float r = (len >= 1) ? chart[layer_start(len)] : NEGV;
        ws[RES_OFF + c] = r;
        if (t == 0) ws[LEN_OFF + b] = (float)len;
    }
}

__global__ __launch_bounds__(64) void finish_kernel(const float* __restrict__ ws,
                                                    float* __restrict__ out) {
    int b = threadIdx.x;  // 0..63
    float diff = ws[RES_OFF + 2 * b + 1] - ws[RES_OFF + 2 * b];
    float len  = ws[LEN_OFF + b];
    for (int d = 32; d > 0; d >>= 1) {
        diff += __shfl_xor(diff, d);
        len  += __shfl_xor(len, d);
    }
    if (b == 0) out[0] = diff / len;
}

extern "C" void kernel_launch(void* const* d_in, const int* in_sizes, int n_in,
                              void* d_out, int out_size, void* d_ws, size_t ws_size,
                              hipStream_t stream) {
    const float* logits    = (const float*)d_in[0];
    const int*   spans_ind = (const int*)d_in[1];
    const void*  maskspan  = d_in[2];
    const void*  span_mask = d_in[3];
    float* ws = (float*)d_ws;

    hipLaunchKernelGGL(cyk_kernel, dim3(NCHART), dim3(1024), 0, stream,
                       logits, spans_ind, maskspan, span_mask, ws);
    hipLaunchKernelGGL(finish_kernel, dim3(1), dim3(64), 0, stream,
                       ws, (float*)d_out);
}